// Round 1
// baseline (37.479 us; speedup 1.0000x reference)
//
#include <hip/hip_runtime.h>

// Euler characteristic curve of sublevel cubical complex.
// x: [B,C,H,W] f32 -> out: [B,C,RES] f32.
// Per-vertex formulation: vertex(+1), right-edge(-1), down-edge(-1), face(+1),
// each binned at ceil(max(corners)*63) clipped to [0,63], then cumsum over bins.

#define BB 32
#define CC 16
#define HH 128
#define WW 128
#define RESB 64
#define NV (HH * WW)
#define NT 256

__global__ __launch_bounds__(NT) void ecc_kernel(const float* __restrict__ X,
                                                 float* __restrict__ out) {
    // Per-thread histogram columns: hist[bin*NT + tid]. Bank = tid%32 -> conflict-free RMW.
    __shared__ int hist[RESB * NT];  // 64 KiB
    const int bc = blockIdx.x;
    const int tid = threadIdx.x;
    const float* __restrict__ x = X + (size_t)bc * NV;

#pragma unroll
    for (int k = 0; k < RESB; ++k) hist[k * NT + tid] = 0;
    __syncthreads();

    for (int idx = tid; idx < NV; idx += NT) {
        const int r = idx >> 7;          // idx / WW
        const int c = idx & (WW - 1);    // idx % WW
        const int cp = (c < WW - 1) ? 1 : 0;   // right neighbor exists
        const int rp = (r < HH - 1) ? WW : 0;  // down neighbor exists (row stride)

        const float x00 = x[idx];
        const float x01 = x[idx + cp];
        const float x10 = x[idx + rp];
        const float x11 = x[idx + rp + cp];

        const float fe_h = fmaxf(x00, x01);               // horizontal edge
        const float fe_v = fmaxf(x00, x10);               // vertical edge
        const float ff   = fmaxf(fe_h, fmaxf(x10, x11));  // face

        // bin(F) = clip(ceil(F*63), 0, 63) -- SCALE=(RES-1)/(T_MAX-T_MIN)=63 exact in f32
        auto bin = [](float F) {
            int t = (int)ceilf(F * 63.0f);
            t = t < 0 ? 0 : t;
            return t > (RESB - 1) ? (RESB - 1) : t;
        };

        if (x00 <= 1.0f) hist[bin(x00) * NT + tid] += 1;           // vertex  (+)
        if (cp && fe_h <= 1.0f) hist[bin(fe_h) * NT + tid] -= 1;   // h-edge  (-)
        if (rp && fe_v <= 1.0f) hist[bin(fe_v) * NT + tid] -= 1;   // v-edge  (-)
        if (cp && rp && ff <= 1.0f) hist[bin(ff) * NT + tid] += 1; // face    (+)
    }
    __syncthreads();

    // Wave 0: lane b reduces bin b across 256 thread-columns.
    // Rotated read order -> bank = (b+k)%32: 2-way aliasing only (free).
    if (tid < 64) {
        const int b = tid;
        int s = 0;
        for (int k = 0; k < NT; ++k) {
            s += hist[b * NT + ((b + k) & (NT - 1))];
        }
        // Inclusive prefix scan across the 64 lanes (= 64 bins) -> cumsum.
        int v = s;
#pragma unroll
        for (int d = 1; d < 64; d <<= 1) {
            int up = __shfl_up(v, d, 64);
            if (tid >= d) v += up;
        }
        out[bc * RESB + b] = (float)v;
    }
}

extern "C" void kernel_launch(void* const* d_in, const int* in_sizes, int n_in,
                              void* d_out, int out_size, void* d_ws, size_t ws_size,
                              hipStream_t stream) {
    const float* x = (const float*)d_in[0];
    float* out = (float*)d_out;
    ecc_kernel<<<BB * CC, NT, 0, stream>>>(x, out);
}

// Round 2
// 22.132 us; speedup vs baseline: 1.6935x; 1.6935x over previous
//
#include <hip/hip_runtime.h>

// Euler characteristic curve of sublevel cubical complex.
// x: [B,C,H,W] f32 -> out: [B,C,RES] f32.
// Kernel 1: per (image, row-slice) block builds a 64-bin signed histogram
//           (per-thread int16 LDS columns, conflict-free), writes partials to ws.
// Kernel 2: per image, sum S partials + 64-lane shfl inclusive scan -> out.

#define BB 32
#define CC 16
#define HH 128
#define WW 128
#define RESB 64
#define NT 256
#define S 4
#define ROWS (HH / S)   // 32 rows per slice
#define BC (BB * CC)

__device__ __forceinline__ int binf(float F) {
    int t = (int)ceilf(F * 63.0f);
    t = t < 0 ? 0 : t;
    return t > (RESB - 1) ? (RESB - 1) : t;
}

__global__ __launch_bounds__(NT) void ecc_hist(const float* __restrict__ X,
                                               int* __restrict__ ws) {
    // Per-thread histogram columns: hist[bin*NT + tid] (int16).
    // RMW addr = bin*512 + 2*tid -> lanes 2k,2k+1 share a dword (single bank row),
    // 64 lanes over 32 banks = 2-way aliasing = free.
    __shared__ short hist[RESB * NT];  // 32 KiB -> 5 blocks/CU
    const int blk = blockIdx.x;
    const int s = blk & (S - 1);
    const int bc = blk >> 2;  // blk / S
    const int tid = threadIdx.x;
    const float* __restrict__ x = X + (size_t)bc * (HH * WW);

    int* h4 = (int*)hist;
#pragma unroll
    for (int k = 0; k < 32; ++k) h4[k * NT + tid] = 0;
    __syncthreads();

    const int col4 = tid & 31;   // which float4 of the row
    const int row0 = tid >> 5;   // 0..7

#pragma unroll
    for (int it = 0; it < ROWS / 8; ++it) {
        const int r = s * ROWS + it * 8 + row0;        // global row (vertex row)
        const int base = r * WW + col4 * 4;
        const float4 a = *(const float4*)(x + base);
        const float aR = x[r * WW + ((col4 < 31) ? col4 * 4 + 4 : WW - 1)];
        const int hasDown = (r < HH - 1) ? 1 : 0;
        const int r1 = hasDown ? r + 1 : r;
        const float4 cv = *(const float4*)(x + r1 * WW + col4 * 4);
        const float cR = x[r1 * WW + ((col4 < 31) ? col4 * 4 + 4 : WW - 1)];

        const float t00[4] = {a.x, a.y, a.z, a.w};
        const float t01[4] = {a.y, a.z, a.w, aR};
        const float t10[4] = {cv.x, cv.y, cv.z, cv.w};
        const float t11[4] = {cv.y, cv.z, cv.w, cR};

#pragma unroll
        for (int k = 0; k < 4; ++k) {
            const int col = col4 * 4 + k;
            const int hasR = (col < WW - 1) ? 1 : 0;
            const float x00 = t00[k];
            const float feh = fmaxf(x00, t01[k]);
            const float fev = fmaxf(x00, t10[k]);
            const float ff  = fmaxf(feh, fmaxf(t10[k], t11[k]));

            const short dv0 = (x00 <= 1.0f) ? 1 : 0;                           // vertex +
            const short dvh = (hasR && feh <= 1.0f) ? -1 : 0;                  // h-edge -
            const short dvv = (hasDown && fev <= 1.0f) ? -1 : 0;               // v-edge -
            const short dvf = (hasR && hasDown && ff <= 1.0f) ? 1 : 0;         // face +

            hist[binf(x00) * NT + tid] += dv0;
            hist[binf(feh) * NT + tid] += dvh;
            hist[binf(fev) * NT + tid] += dvv;
            hist[binf(ff)  * NT + tid] += dvf;
        }
    }
    __syncthreads();

    // Parallel reduce: thread (bin = tid&63, q = tid>>6) sums 64 shorts
    // (= 32 dwords) of its bin row, rotated by bin -> 2-way bank aliasing only.
    const int bin = tid & 63;
    const int q = tid >> 6;
    const int* hrow = (const int*)hist + bin * (NT / 2);  // 128 dwords per bin
    int partial = 0;
#pragma unroll
    for (int k = 0; k < 32; ++k) {
        const int d = q * 32 + ((k + bin) & 31);
        const int v = hrow[d];
        partial += (int)(short)(v & 0xffff) + (v >> 16);
    }
    __syncthreads();
    ((int*)hist)[tid] = partial;  // reuse hist space for quarter partials
    __syncthreads();
    if (tid < RESB) {
        const int* p = (const int*)hist;
        const int tot = p[tid] + p[tid + 64] + p[tid + 128] + p[tid + 192];
        ws[blk * RESB + tid] = tot;
    }
}

__global__ __launch_bounds__(64) void ecc_scan(const int* __restrict__ ws,
                                               float* __restrict__ out) {
    const int bc = blockIdx.x;
    const int b = threadIdx.x;  // bin
    int v = 0;
#pragma unroll
    for (int si = 0; si < S; ++si) v += ws[(bc * S + si) * RESB + b];
    // Inclusive prefix scan over 64 lanes (= 64 bins) -> cumsum.
#pragma unroll
    for (int d = 1; d < 64; d <<= 1) {
        const int up = __shfl_up(v, d, 64);
        if (b >= d) v += up;
    }
    out[bc * RESB + b] = (float)v;
}

extern "C" void kernel_launch(void* const* d_in, const int* in_sizes, int n_in,
                              void* d_out, int out_size, void* d_ws, size_t ws_size,
                              hipStream_t stream) {
    const float* x = (const float*)d_in[0];
    float* out = (float*)d_out;
    int* ws = (int*)d_ws;  // BC*S*RESB ints = 512 KiB
    ecc_hist<<<BC * S, NT, 0, stream>>>(x, ws);
    ecc_scan<<<BC, 64, 0, stream>>>(ws, out);
}

// Round 3
// 15.116 us; speedup vs baseline: 2.4793x; 1.4641x over previous
//
#include <hip/hip_runtime.h>

// Euler characteristic curve of sublevel cubical complex.
// x: [B,C,H,W] f32 -> out: [B,C,RES] f32.
// Kernel 1: per (image, row-slice) block builds a 64-bin signed histogram.
//   hist[bin][lane] int32 in LDS (16 KiB), updated with ds_add atomics
//   (no RMW dependency chains, no intra-wave same-address collisions).
//   Bins computed once per vertex; edge/face bins via integer max
//   (bin is monotone, so bin(max(a,b)) == max(bin(a),bin(b))).
// Kernel 2: per image, sum S partials + 64-lane shfl inclusive scan -> out.

#define BB 32
#define CC 16
#define HH 128
#define WW 128
#define RESB 64
#define NT 256
#define S 4
#define ROWS (HH / S)    // 32 rows per slice
#define RPT (ROWS / 8)   // 4 consecutive rows per thread
#define BC (BB * CC)

__device__ __forceinline__ int binq(float F) {
    int t = (int)ceilf(F * 63.0f);
    t = t < 0 ? 0 : t;
    return t > (RESB - 1) ? (RESB - 1) : t;
}

__global__ __launch_bounds__(NT, 8) void ecc_hist(const float* __restrict__ X,
                                                  int* __restrict__ ws) {
    __shared__ int hist[RESB * 64];  // [bin][lane], 16 KiB -> 8 blocks/CU
    const int blk = blockIdx.x;
    const int sl = blk & (S - 1);
    const int bc = blk >> 2;  // blk / S
    const int tid = threadIdx.x;
    const int lane = tid & 63;
    const float* __restrict__ x = X + (size_t)bc * (HH * WW);

    {
        int4* h4 = (int4*)hist;
#pragma unroll
        for (int k = 0; k < 4; ++k) h4[k * NT + tid] = make_int4(0, 0, 0, 0);
    }
    __syncthreads();

    const int col4 = tid & 31;   // which float4 of the row
    const int tr = tid >> 5;     // 0..7 thread-row group
    const int r0 = sl * ROWS + tr * RPT;
    const int c0 = col4 * 4;
    const int cR = (col4 < 31) ? c0 + 4 : WW - 1;  // right-neighbor col (clamped; masked at k=3)

    int u[5], v[5];
    {
        const float4 a = *(const float4*)(x + r0 * WW + c0);
        const float aR = x[r0 * WW + cR];
        u[0] = binq(a.x); u[1] = binq(a.y); u[2] = binq(a.z); u[3] = binq(a.w); u[4] = binq(aR);
    }

#pragma unroll
    for (int dr = 0; dr < RPT; ++dr) {
        const int r = r0 + dr;
        const int hasDown = (r < HH - 1) ? 1 : 0;
        const int r1 = hasDown ? r + 1 : r;  // last image row: dup (masked)
        {
            const float4 b = *(const float4*)(x + r1 * WW + c0);
            const float bR = x[r1 * WW + cR];
            v[0] = binq(b.x); v[1] = binq(b.y); v[2] = binq(b.z); v[3] = binq(b.w); v[4] = binq(bR);
        }
#pragma unroll
        for (int k = 0; k < 4; ++k) {
            const int hasR = (c0 + k < WW - 1) ? 1 : 0;
            const int u00 = u[k];
            const int bh  = max(u00, u[k + 1]);
            const int bvv = max(u00, v[k]);
            const int bf  = max(bh, max(v[k], v[k + 1]));
            atomicAdd(&hist[u00 * 64 + lane], 1);                          // vertex +
            atomicAdd(&hist[bh  * 64 + lane], hasR ? -1 : 0);              // h-edge -
            atomicAdd(&hist[bvv * 64 + lane], hasDown ? -1 : 0);           // v-edge -
            atomicAdd(&hist[bf  * 64 + lane], (hasR & hasDown) ? 1 : 0);   // face +
        }
#pragma unroll
        for (int k = 0; k < 5; ++k) u[k] = v[k];
    }
    __syncthreads();

    // Reduce over 64 lane-columns: thread (bin = tid&63, q = tid>>6) sums 16,
    // rotated by bin to spread banks.
    const int bin = tid & 63;
    const int q = tid >> 6;
    int ssum = 0;
#pragma unroll
    for (int k = 0; k < 16; ++k) {
        ssum += hist[bin * 64 + q * 16 + ((k + bin) & 15)];
    }
    __syncthreads();
    hist[tid] = ssum;  // partial at [q*64 + bin]
    __syncthreads();
    if (tid < RESB) {
        ws[blk * RESB + tid] = hist[tid] + hist[tid + 64] + hist[tid + 128] + hist[tid + 192];
    }
}

__global__ __launch_bounds__(64) void ecc_scan(const int* __restrict__ ws,
                                               float* __restrict__ out) {
    const int bc = blockIdx.x;
    const int b = threadIdx.x;  // bin
    int v = 0;
#pragma unroll
    for (int si = 0; si < S; ++si) v += ws[(bc * S + si) * RESB + b];
    // Inclusive prefix scan over 64 lanes (= 64 bins) -> cumsum.
#pragma unroll
    for (int d = 1; d < 64; d <<= 1) {
        const int up = __shfl_up(v, d, 64);
        if (b >= d) v += up;
    }
    out[bc * RESB + b] = (float)v;
}

extern "C" void kernel_launch(void* const* d_in, const int* in_sizes, int n_in,
                              void* d_out, int out_size, void* d_ws, size_t ws_size,
                              hipStream_t stream) {
    const float* x = (const float*)d_in[0];
    float* out = (float*)d_out;
    int* ws = (int*)d_ws;  // BC*S*RESB ints = 512 KiB
    ecc_hist<<<BC * S, NT, 0, stream>>>(x, ws);
    ecc_scan<<<BC, 64, 0, stream>>>(ws, out);
}